// Round 13
// baseline (35.496 us; speedup 1.0000x reference)
//
#include <hip/hip_runtime.h>
#include <hip/hip_bf16.h>
#include <stdint.h>

// Problem constants (from reference)
#define N_SAMP 16384
#define DCONT  64
#define DCAT   2000
#define EMB    64
#define BM 32                   // rows per block
#define NT_TOT 66               // 64 cat K-steps of 32 (permuted) + 2 cont steps

typedef short bf16x8 __attribute__((ext_vector_type(8)));
typedef float f32x4  __attribute__((ext_vector_type(4)));
typedef unsigned long long ull;

__device__ __forceinline__ uint16_t f2bf(float f) {
    union { float f; uint32_t u; } v; v.f = f;
    uint32_t r = v.u + 0x7FFFu + ((v.u >> 16) & 1u);   // RNE
    return (uint16_t)(r >> 16);
}
__device__ __forceinline__ uint32_t pack2f(float a, float b) {
    return (uint32_t)f2bf(a) | ((uint32_t)f2bf(b) << 16);
}

// Build B in MFMA FRAGMENT ORDER: BF[t][n][lane] = 8 bf16 (16 B).
// Step t, col-frag n, lane (g=lane>>4, lr=lane&15) holds col c=n*16+lr,
// permuted-k p = t*32 + g*8 + j (j=0..7).
//   p < 2048 : cat. Bit b of mask word W (p=32W+b) maps to
//              kc = 256*(W>>3) + 128*(W&1) + 4*b + ((W>>1)&3)  [validated R8-R12]
//   p >= 2048: W_cont[p-2048][c]
__global__ void build_bfrag_kernel(const float* __restrict__ Wcont,
                                   const float* __restrict__ Wcat,
                                   uint16_t* __restrict__ BF) {
    const int t = blockIdx.x, n = blockIdx.y;
    const int lane = threadIdx.x;
    const int g = lane >> 4, lr = lane & 15;
    const int c = n * 16 + lr;
    uint16_t vals[8];
    #pragma unroll
    for (int j = 0; j < 8; ++j) {
        const int p = t * 32 + g * 8 + j;
        float v = 0.f;
        if (p < 2048) {
            const int W = p >> 5, b = p & 31;
            const int kc = 256 * (W >> 3) + 128 * (W & 1) + 4 * b + ((W >> 1) & 3);
            if (kc < DCAT) v = Wcat[(long)kc * EMB + c];
        } else {
            v = Wcont[(long)(p - 2048) * EMB + c];
        }
        vals[j] = f2bf(v);
    }
    *(int4*)(BF + ((long)(t * 4 + n) * 64 + lane) * 8) = *(const int4*)vals;
}

struct BFrag { bf16x8 b0, b1, b2, b3; };       // 4 col-frags, contiguous 4KB in BF

__global__ __launch_bounds__(256, 2)
void fm_fused(const float* __restrict__ xc,
              const int*   __restrict__ xcat,
              const uint16_t* __restrict__ BF,
              float* __restrict__ out) {
    // Wave-independent: wave w compresses xcat cols [512w,512w+512) of all 32
    // rows into its private LDS strip, then runs its K-quarter MFMA.
    // Phase-1 is SOFTWARE-PIPELINED 2-deep (issue group g+1 before processing
    // group g) so each wave always keeps ~16KB of loads in flight.
    __shared__ uint32_t maskL[4][BM][17];      // 8.5 KB, per-wave strips
    __shared__ float    part[4][BM][EMB];      // 32 KB

    const int tid  = threadIdx.x;
    const int w    = tid >> 6;
    const int lane = tid & 63;
    const int g    = lane >> 4;
    const int lr   = lane & 15;
    const int r0   = blockIdx.x * BM;

    const int t0i = w * 16;
    BFrag bb0, bb1;
    auto loadBF = [&](int t) -> BFrag {
        const uint16_t* base = BF + (long)t * 2048 + lane * 8;   // frag-ordered
        BFrag f;
        f.b0 = *(const bf16x8*)(base);                            // 1KB contiguous
        f.b1 = *(const bf16x8*)(base + 512);
        f.b2 = *(const bf16x8*)(base + 1024);
        f.b3 = *(const bf16x8*)(base + 1536);
        return f;
    };

    // ---- Phase 1 (wave-private, pipelined): compress 32 rows x 512 cols
    const int* bp = xcat + (long)r0 * DCAT + 512 * w + lane * 4;
    int4 vaA[4], vbA[4], vaB[4], vbB[4];

    auto loadGrp = [&](int r4, int4* A, int4* B) {
        #pragma unroll
        for (int rr = 0; rr < 4; ++rr) {
            const int* rp = bp + (long)(r4 + rr) * DCAT;
            A[rr] = *(const int4*)(rp);
            B[rr] = (w < 3 || lane < 52) ? *(const int4*)(rp + 256)
                                         : make_int4(0, 0, 0, 0);
        }
    };
    auto procGrp = [&](int r4, const int4* A, const int4* B) {
        #pragma unroll
        for (int rr = 0; rr < 4; ++rr) {
            ull a0 = __ballot(A[rr].x != 0), a1 = __ballot(A[rr].y != 0);
            ull a2 = __ballot(A[rr].z != 0), a3 = __ballot(A[rr].w != 0);
            ull c0 = __ballot(B[rr].x != 0), c1 = __ballot(B[rr].y != 0);
            ull c2 = __ballot(B[rr].z != 0), c3 = __ballot(B[rr].w != 0);
            // every lane computes word 16w + (lane&15); lanes 0..15 store strip
            ull s0 = (lane & 8) ? c0 : a0;
            ull s1 = (lane & 8) ? c1 : a1;
            ull s2 = (lane & 8) ? c2 : a2;
            ull s3 = (lane & 8) ? c3 : a3;
            ull t0 = (lane & 2) ? s1 : s0;
            ull t1 = (lane & 2) ? s3 : s2;
            ull t  = (lane & 4) ? t1 : t0;
            uint32_t val = (lane & 1) ? (uint32_t)(t >> 32) : (uint32_t)t;
            if (lane < 16) maskL[w][r4 + rr][lane] = val;
        }
    };

    loadGrp(0, vaA, vbA);
    #pragma unroll
    for (int gix = 0; gix < 8; ++gix) {
        int4* curA = (gix & 1) ? vaB : vaA;
        int4* curB = (gix & 1) ? vbB : vbA;
        int4* nxtA = (gix & 1) ? vaA : vaB;
        int4* nxtB = (gix & 1) ? vbA : vbB;
        if (gix + 1 < 8) {
            loadGrp((gix + 1) * 4, nxtA, nxtB);
        } else {
            bb0 = loadBF(t0i);            // prefetch B frags during last group
            bb1 = loadBF(t0i + 1);
        }
        __builtin_amdgcn_sched_barrier(0);   // pin: next-group loads issued above
        procGrp(gix * 4, curA, curB);
    }

    // ---- this wave's mask regs (same-wave producer: lgkmcnt only, no barrier)
    int4 m0[4], m1[4];
    #pragma unroll
    for (int q = 0; q < 4; ++q) {
        m0[q] = *(const int4*)&maskL[w][lr][4 * q];
        m1[q] = *(const int4*)&maskL[w][16 + lr][4 * q];
    }

    f32x4 acc[2][4] = { { {0,0,0,0},{0,0,0,0},{0,0,0,0},{0,0,0,0} },
                        { {0,0,0,0},{0,0,0,0},{0,0,0,0},{0,0,0,0} } };

    auto expand = [&](uint32_t word) -> bf16x8 {
        const uint32_t b = (word >> (g * 8)) & 0xFFu;
        union { uint32_t u[4]; bf16x8 v; } cv;
        #pragma unroll
        for (int j = 0; j < 4; ++j) {
            const uint32_t b0 = (b >> (2 * j)) & 1u;
            const uint32_t b1 = (b >> (2 * j + 1)) & 1u;
            cv.u[j] = (b0 + (b1 << 16)) * 0x3F80u;
        }
        return cv.v;
    };
    auto mmac = [&](bf16x8 af0, bf16x8 af1, const BFrag& B) {
        acc[0][0] = __builtin_amdgcn_mfma_f32_16x16x32_bf16(af0, B.b0, acc[0][0], 0, 0, 0);
        acc[0][1] = __builtin_amdgcn_mfma_f32_16x16x32_bf16(af0, B.b1, acc[0][1], 0, 0, 0);
        acc[0][2] = __builtin_amdgcn_mfma_f32_16x16x32_bf16(af0, B.b2, acc[0][2], 0, 0, 0);
        acc[0][3] = __builtin_amdgcn_mfma_f32_16x16x32_bf16(af0, B.b3, acc[0][3], 0, 0, 0);
        acc[1][0] = __builtin_amdgcn_mfma_f32_16x16x32_bf16(af1, B.b0, acc[1][0], 0, 0, 0);
        acc[1][1] = __builtin_amdgcn_mfma_f32_16x16x32_bf16(af1, B.b1, acc[1][1], 0, 0, 0);
        acc[1][2] = __builtin_amdgcn_mfma_f32_16x16x32_bf16(af1, B.b2, acc[1][2], 0, 0, 0);
        acc[1][3] = __builtin_amdgcn_mfma_f32_16x16x32_bf16(af1, B.b3, acc[1][3], 0, 0, 0);
    };

    // ---- main loop: 16 K-steps; B 2-deep register pipeline; no barriers
    #pragma unroll
    for (int s = 0; s < 16; ++s) {
        const int q = s >> 2, r = s & 3;
        uint32_t w0, w1;
        w0 = (r == 0) ? m0[q].x : (r == 1) ? m0[q].y : (r == 2) ? m0[q].z : m0[q].w;
        w1 = (r == 0) ? m1[q].x : (r == 1) ? m1[q].y : (r == 2) ? m1[q].z : m1[q].w;
        bf16x8 af0 = expand(w0);
        bf16x8 af1 = expand(w1);
        __builtin_amdgcn_sched_barrier(0);
        if (s & 1) { mmac(af0, af1, bb1); if (s + 2 < 16) bb1 = loadBF(t0i + s + 2); }
        else       { mmac(af0, af1, bb0); if (s + 2 < 16) bb0 = loadBF(t0i + s + 2); }
        __builtin_amdgcn_sched_barrier(0);
    }

    // ---- continuous part: waves 2,3 take steps t=64,65
    if (w >= 2) {
        const int cs = w - 2;
        const float* xP0 = xc + (long)(r0 + lr) * DCONT + cs * 32 + g * 8;
        const float* xP1 = xc + (long)(r0 + 16 + lr) * DCONT + cs * 32 + g * 8;
        float4 x0 = *(const float4*)(xP0);
        float4 x1 = *(const float4*)(xP0 + 4);
        float4 x2 = *(const float4*)(xP1);
        float4 x3 = *(const float4*)(xP1 + 4);
        BFrag bc = loadBF(64 + cs);
        union { uint32_t u[4]; bf16x8 v; } c0, c1;
        c0.u[0] = pack2f(x0.x, x0.y); c0.u[1] = pack2f(x0.z, x0.w);
        c0.u[2] = pack2f(x1.x, x1.y); c0.u[3] = pack2f(x1.z, x1.w);
        c1.u[0] = pack2f(x2.x, x2.y); c1.u[1] = pack2f(x2.z, x2.w);
        c1.u[2] = pack2f(x3.x, x3.y); c1.u[3] = pack2f(x3.z, x3.w);
        mmac(c0.v, c1.v, bc);
    }

    // ---- epilogue: combine 4 wave-partials; out[r] = 0.5*||s_row||^2
    // lane (g,lr): rows rf*16 + g*4 + r, col n*16 + lr
    #pragma unroll
    for (int rf = 0; rf < 2; ++rf)
        #pragma unroll
        for (int n = 0; n < 4; ++n)
            #pragma unroll
            for (int r = 0; r < 4; ++r)
                part[w][rf * 16 + g * 4 + r][n * 16 + lr] = acc[rf][n][r];
    __syncthreads();

    const int row = tid >> 3;           // 0..31
    const int c0i = (tid & 7) * 8;      // 8 cols per thread
    float p = 0.f;
    #pragma unroll
    for (int h = 0; h < 2; ++h) {
        float4 v0 = *(const float4*)&part[0][row][c0i + h * 4];
        float4 v1 = *(const float4*)&part[1][row][c0i + h * 4];
        float4 v2 = *(const float4*)&part[2][row][c0i + h * 4];
        float4 v3 = *(const float4*)&part[3][row][c0i + h * 4];
        float sx = v0.x + v1.x + v2.x + v3.x;
        float sy = v0.y + v1.y + v2.y + v3.y;
        float sz = v0.z + v1.z + v2.z + v3.z;
        float sw_ = v0.w + v1.w + v2.w + v3.w;
        p += sx * sx + sy * sy + sz * sz + sw_ * sw_;
    }
    p += __shfl_xor(p, 1);
    p += __shfl_xor(p, 2);
    p += __shfl_xor(p, 4);
    if ((tid & 7) == 0) out[r0 + row] = 0.5f * p;
}

extern "C" void kernel_launch(void* const* d_in, const int* in_sizes, int n_in,
                              void* d_out, int out_size, void* d_ws, size_t ws_size,
                              hipStream_t stream) {
    const float* xc    = (const float*)d_in[0];   // data_continuous [N,64] f32
    const int*   xcat  = (const int*)d_in[1];     // data_category   [N,2000] i32
    const float* Wcont = (const float*)d_in[2];   // [64,64] f32
    const float* Wcat  = (const float*)d_in[3];   // [2000,64] f32
    uint16_t* BF = (uint16_t*)d_ws;               // fragment-ordered B: 66*4*64*16B = 270 KiB
    float* outp = (float*)d_out;

    build_bfrag_kernel<<<dim3(NT_TOT, 4), 64, 0, stream>>>(Wcont, Wcat, BF);
    fm_fused<<<N_SAMP / BM, 256, 0, stream>>>(xc, xcat, BF, outp);
}

// Round 14
// 34.320 us; speedup vs baseline: 1.0343x; 1.0343x over previous
//
#include <hip/hip_runtime.h>
#include <hip/hip_bf16.h>
#include <stdint.h>

// Problem constants (from reference)
#define N_SAMP 16384
#define DCONT  64
#define DCAT   2000
#define EMB    64
#define BM 32                   // rows per block
#define NT_TOT 66               // 64 cat K-steps of 32 (permuted) + 2 cont steps

typedef short bf16x8 __attribute__((ext_vector_type(8)));
typedef float f32x4  __attribute__((ext_vector_type(4)));
typedef int   v4i    __attribute__((ext_vector_type(4)));
typedef unsigned long long ull;

__device__ __forceinline__ uint16_t f2bf(float f) {
    union { float f; uint32_t u; } v; v.f = f;
    uint32_t r = v.u + 0x7FFFu + ((v.u >> 16) & 1u);   // RNE
    return (uint16_t)(r >> 16);
}
__device__ __forceinline__ uint32_t pack2f(float a, float b) {
    return (uint32_t)f2bf(a) | ((uint32_t)f2bf(b) << 16);
}
// Non-temporal 16B load: xcat is stream-once -> bypass L2 fill, keep L2 for B.
__device__ __forceinline__ v4i ntload4(const int* p) {
    return __builtin_nontemporal_load((const v4i*)p);
}

// Build B in MFMA FRAGMENT ORDER: BF[t][n][lane] = 8 bf16 (16 B).
// Step t, col-frag n, lane (g=lane>>4, lr=lane&15) holds col c=n*16+lr,
// permuted-k p = t*32 + g*8 + j (j=0..7).
//   p < 2048 : cat. Bit b of mask word W (p=32W+b) maps to
//              kc = 256*(W>>3) + 128*(W&1) + 4*b + ((W>>1)&3)  [validated R8-R13]
//   p >= 2048: W_cont[p-2048][c]
__global__ void build_bfrag_kernel(const float* __restrict__ Wcont,
                                   const float* __restrict__ Wcat,
                                   uint16_t* __restrict__ BF) {
    const int t = blockIdx.x, n = blockIdx.y;
    const int lane = threadIdx.x;
    const int g = lane >> 4, lr = lane & 15;
    const int c = n * 16 + lr;
    uint16_t vals[8];
    #pragma unroll
    for (int j = 0; j < 8; ++j) {
        const int p = t * 32 + g * 8 + j;
        float v = 0.f;
        if (p < 2048) {
            const int W = p >> 5, b = p & 31;
            const int kc = 256 * (W >> 3) + 128 * (W & 1) + 4 * b + ((W >> 1) & 3);
            if (kc < DCAT) v = Wcat[(long)kc * EMB + c];
        } else {
            v = Wcont[(long)(p - 2048) * EMB + c];
        }
        vals[j] = f2bf(v);
    }
    *(int4*)(BF + ((long)(t * 4 + n) * 64 + lane) * 8) = *(const int4*)vals;
}

struct BFrag { bf16x8 b0, b1, b2, b3; };       // 4 col-frags, contiguous 4KB in BF

__global__ __launch_bounds__(256, 2)
void fm_fused(const float* __restrict__ xc,
              const int*   __restrict__ xcat,
              const uint16_t* __restrict__ BF,
              float* __restrict__ out) {
    // Wave-independent: wave w compresses xcat cols [512w,512w+512) of all 32
    // rows into its private LDS strip, then runs its K-quarter MFMA.
    // Phase-1 pipelined 2-deep; xcat reads are NON-TEMPORAL (no L2 fill) so
    // the B fragment panel stays L2-resident for phase 2.
    __shared__ uint32_t maskL[4][BM][17];      // 8.5 KB, per-wave strips
    __shared__ float    part[4][BM][EMB];      // 32 KB

    const int tid  = threadIdx.x;
    const int w    = tid >> 6;
    const int lane = tid & 63;
    const int g    = lane >> 4;
    const int lr   = lane & 15;
    const int r0   = blockIdx.x * BM;

    const int t0i = w * 16;
    BFrag bb0, bb1;
    auto loadBF = [&](int t) -> BFrag {
        const uint16_t* base = BF + (long)t * 2048 + lane * 8;   // frag-ordered
        BFrag f;
        f.b0 = *(const bf16x8*)(base);                            // 1KB contiguous
        f.b1 = *(const bf16x8*)(base + 512);
        f.b2 = *(const bf16x8*)(base + 1024);
        f.b3 = *(const bf16x8*)(base + 1536);
        return f;
    };

    // ---- Phase 1 (wave-private, pipelined): compress 32 rows x 512 cols
    const int* bp = xcat + (long)r0 * DCAT + 512 * w + lane * 4;
    v4i vaA[4], vbA[4], vaB[4], vbB[4];
    const v4i vzero = { 0, 0, 0, 0 };

    auto loadGrp = [&](int r4, v4i* A, v4i* B) {
        #pragma unroll
        for (int rr = 0; rr < 4; ++rr) {
            const int* rp = bp + (long)(r4 + rr) * DCAT;
            A[rr] = ntload4(rp);
            B[rr] = (w < 3 || lane < 52) ? ntload4(rp + 256) : vzero;
        }
    };
    auto procGrp = [&](int r4, const v4i* A, const v4i* B) {
        #pragma unroll
        for (int rr = 0; rr < 4; ++rr) {
            ull a0 = __ballot(A[rr].x != 0), a1 = __ballot(A[rr].y != 0);
            ull a2 = __ballot(A[rr].z != 0), a3 = __ballot(A[rr].w != 0);
            ull c0 = __ballot(B[rr].x != 0), c1 = __ballot(B[rr].y != 0);
            ull c2 = __ballot(B[rr].z != 0), c3 = __ballot(B[rr].w != 0);
            // every lane computes word 16w + (lane&15); lanes 0..15 store strip
            ull s0 = (lane & 8) ? c0 : a0;
            ull s1 = (lane & 8) ? c1 : a1;
            ull s2 = (lane & 8) ? c2 : a2;
            ull s3 = (lane & 8) ? c3 : a3;
            ull t0 = (lane & 2) ? s1 : s0;
            ull t1 = (lane & 2) ? s3 : s2;
            ull t  = (lane & 4) ? t1 : t0;
            uint32_t val = (lane & 1) ? (uint32_t)(t >> 32) : (uint32_t)t;
            if (lane < 16) maskL[w][r4 + rr][lane] = val;
        }
    };

    loadGrp(0, vaA, vbA);
    #pragma unroll
    for (int gix = 0; gix < 8; ++gix) {
        v4i* curA = (gix & 1) ? vaB : vaA;
        v4i* curB = (gix & 1) ? vbB : vbA;
        v4i* nxtA = (gix & 1) ? vaA : vaB;
        v4i* nxtB = (gix & 1) ? vbA : vbB;
        if (gix + 1 < 8) {
            loadGrp((gix + 1) * 4, nxtA, nxtB);
        } else {
            bb0 = loadBF(t0i);            // prefetch B frags during last group
            bb1 = loadBF(t0i + 1);
        }
        __builtin_amdgcn_sched_barrier(0);   // pin: next-group loads issued above
        procGrp(gix * 4, curA, curB);
    }

    // ---- this wave's mask regs (same-wave producer: lgkmcnt only, no barrier)
    int4 m0[4], m1[4];
    #pragma unroll
    for (int q = 0; q < 4; ++q) {
        m0[q] = *(const int4*)&maskL[w][lr][4 * q];
        m1[q] = *(const int4*)&maskL[w][16 + lr][4 * q];
    }

    f32x4 acc[2][4] = { { {0,0,0,0},{0,0,0,0},{0,0,0,0},{0,0,0,0} },
                        { {0,0,0,0},{0,0,0,0},{0,0,0,0},{0,0,0,0} } };

    auto expand = [&](uint32_t word) -> bf16x8 {
        const uint32_t b = (word >> (g * 8)) & 0xFFu;
        union { uint32_t u[4]; bf16x8 v; } cv;
        #pragma unroll
        for (int j = 0; j < 4; ++j) {
            const uint32_t b0 = (b >> (2 * j)) & 1u;
            const uint32_t b1 = (b >> (2 * j + 1)) & 1u;
            cv.u[j] = (b0 + (b1 << 16)) * 0x3F80u;
        }
        return cv.v;
    };
    auto mmac = [&](bf16x8 af0, bf16x8 af1, const BFrag& B) {
        acc[0][0] = __builtin_amdgcn_mfma_f32_16x16x32_bf16(af0, B.b0, acc[0][0], 0, 0, 0);
        acc[0][1] = __builtin_amdgcn_mfma_f32_16x16x32_bf16(af0, B.b1, acc[0][1], 0, 0, 0);
        acc[0][2] = __builtin_amdgcn_mfma_f32_16x16x32_bf16(af0, B.b2, acc[0][2], 0, 0, 0);
        acc[0][3] = __builtin_amdgcn_mfma_f32_16x16x32_bf16(af0, B.b3, acc[0][3], 0, 0, 0);
        acc[1][0] = __builtin_amdgcn_mfma_f32_16x16x32_bf16(af1, B.b0, acc[1][0], 0, 0, 0);
        acc[1][1] = __builtin_amdgcn_mfma_f32_16x16x32_bf16(af1, B.b1, acc[1][1], 0, 0, 0);
        acc[1][2] = __builtin_amdgcn_mfma_f32_16x16x32_bf16(af1, B.b2, acc[1][2], 0, 0, 0);
        acc[1][3] = __builtin_amdgcn_mfma_f32_16x16x32_bf16(af1, B.b3, acc[1][3], 0, 0, 0);
    };

    // ---- main loop: 16 K-steps; B 2-deep register pipeline; no barriers
    #pragma unroll
    for (int s = 0; s < 16; ++s) {
        const int q = s >> 2, r = s & 3;
        uint32_t w0, w1;
        w0 = (r == 0) ? m0[q].x : (r == 1) ? m0[q].y : (r == 2) ? m0[q].z : m0[q].w;
        w1 = (r == 0) ? m1[q].x : (r == 1) ? m1[q].y : (r == 2) ? m1[q].z : m1[q].w;
        bf16x8 af0 = expand(w0);
        bf16x8 af1 = expand(w1);
        __builtin_amdgcn_sched_barrier(0);
        if (s & 1) { mmac(af0, af1, bb1); if (s + 2 < 16) bb1 = loadBF(t0i + s + 2); }
        else       { mmac(af0, af1, bb0); if (s + 2 < 16) bb0 = loadBF(t0i + s + 2); }
        __builtin_amdgcn_sched_barrier(0);
    }

    // ---- continuous part: waves 2,3 take steps t=64,65
    if (w >= 2) {
        const int cs = w - 2;
        const float* xP0 = xc + (long)(r0 + lr) * DCONT + cs * 32 + g * 8;
        const float* xP1 = xc + (long)(r0 + 16 + lr) * DCONT + cs * 32 + g * 8;
        float4 x0 = *(const float4*)(xP0);
        float4 x1 = *(const float4*)(xP0 + 4);
        float4 x2 = *(const float4*)(xP1);
        float4 x3 = *(const float4*)(xP1 + 4);
        BFrag bc = loadBF(64 + cs);
        union { uint32_t u[4]; bf16x8 v; } c0, c1;
        c0.u[0] = pack2f(x0.x, x0.y); c0.u[1] = pack2f(x0.z, x0.w);
        c0.u[2] = pack2f(x1.x, x1.y); c0.u[3] = pack2f(x1.z, x1.w);
        c1.u[0] = pack2f(x2.x, x2.y); c1.u[1] = pack2f(x2.z, x2.w);
        c1.u[2] = pack2f(x3.x, x3.y); c1.u[3] = pack2f(x3.z, x3.w);
        mmac(c0.v, c1.v, bc);
    }

    // ---- epilogue: combine 4 wave-partials; out[r] = 0.5*||s_row||^2
    // lane (g,lr): rows rf*16 + g*4 + r, col n*16 + lr
    #pragma unroll
    for (int rf = 0; rf < 2; ++rf)
        #pragma unroll
        for (int n = 0; n < 4; ++n)
            #pragma unroll
            for (int r = 0; r < 4; ++r)
                part[w][rf * 16 + g * 4 + r][n * 16 + lr] = acc[rf][n][r];
    __syncthreads();

    const int row = tid >> 3;           // 0..31
    const int c0i = (tid & 7) * 8;      // 8 cols per thread
    float p = 0.f;
    #pragma unroll
    for (int h = 0; h < 2; ++h) {
        float4 v0 = *(const float4*)&part[0][row][c0i + h * 4];
        float4 v1 = *(const float4*)&part[1][row][c0i + h * 4];
        float4 v2 = *(const float4*)&part[2][row][c0i + h * 4];
        float4 v3 = *(const float4*)&part[3][row][c0i + h * 4];
        float sx = v0.x + v1.x + v2.x + v3.x;
        float sy = v0.y + v1.y + v2.y + v3.y;
        float sz = v0.z + v1.z + v2.z + v3.z;
        float sw_ = v0.w + v1.w + v2.w + v3.w;
        p += sx * sx + sy * sy + sz * sz + sw_ * sw_;
    }
    p += __shfl_xor(p, 1);
    p += __shfl_xor(p, 2);
    p += __shfl_xor(p, 4);
    if ((tid & 7) == 0) out[r0 + row] = 0.5f * p;
}

extern "C" void kernel_launch(void* const* d_in, const int* in_sizes, int n_in,
                              void* d_out, int out_size, void* d_ws, size_t ws_size,
                              hipStream_t stream) {
    const float* xc    = (const float*)d_in[0];   // data_continuous [N,64] f32
    const int*   xcat  = (const int*)d_in[1];     // data_category   [N,2000] i32
    const float* Wcont = (const float*)d_in[2];   // [64,64] f32
    const float* Wcat  = (const float*)d_in[3];   // [2000,64] f32
    uint16_t* BF = (uint16_t*)d_ws;               // fragment-ordered B: 66*4*64*16B = 270 KiB
    float* outp = (float*)d_out;

    build_bfrag_kernel<<<dim3(NT_TOT, 4), 64, 0, stream>>>(Wcont, Wcat, BF);
    fm_fused<<<N_SAMP / BM, 256, 0, stream>>>(xc, xcat, BF, outp);
}